// Round 12
// baseline (167.517 us; speedup 1.0000x reference)
//
#include <hip/hip_runtime.h>
#include <cstdint>
#include <cstddef>
#include <cmath>

// ---------- types ----------
typedef float f32x4 __attribute__((ext_vector_type(4)));
typedef int   i32x4 __attribute__((ext_vector_type(4)));
typedef int   i32x8 __attribute__((ext_vector_type(8)));

// ---------- pass 1: f32 -> fp8 e4m3 (X), rint+fp8 (W_ampa, W_shunt) ----------
__global__ void convert_all(const float4* __restrict__ X,
                            const float4* __restrict__ Wa,
                            const float4* __restrict__ Ws,
                            unsigned long long* __restrict__ Xq,
                            unsigned long long* __restrict__ Waq,
                            unsigned long long* __restrict__ Wsq) {
    int i = blockIdx.x * 256 + threadIdx.x;
    const float4* s; unsigned long long* d; int t; bool rnd;
    if (i < 1048576)      { s = X;  d = Xq;  t = i;           rnd = false; }
    else if (i < 1572864) { s = Wa; d = Waq; t = i - 1048576; rnd = true;  }
    else                  { s = Ws; d = Wsq; t = i - 1572864; rnd = true;  }
    float4 a = s[2 * t], b = s[2 * t + 1];
    if (rnd) {
        a.x = rintf(a.x); a.y = rintf(a.y); a.z = rintf(a.z); a.w = rintf(a.w);
        b.x = rintf(b.x); b.y = rintf(b.y); b.z = rintf(b.z); b.w = rintf(b.w);
    }
    int w0 = __builtin_amdgcn_cvt_pk_fp8_f32(a.x, a.y, 0, false);
    w0     = __builtin_amdgcn_cvt_pk_fp8_f32(a.z, a.w, w0, true);
    int w1 = __builtin_amdgcn_cvt_pk_fp8_f32(b.x, b.y, 0, false);
    w1     = __builtin_amdgcn_cvt_pk_fp8_f32(b.z, b.w, w1, true);
    d[t] = ((unsigned long long)(unsigned int)w1 << 32) | (unsigned int)w0;
}

// ---------- pass 2: fused dual-GEMM (MX-fp8 K=128) + DPI neuron update ----------
// R12: GEMM reverted to R10's verified fp8xfp8 (R11's fp4 B-operand had a
// within-lane element-order mismatch -> numSyn err ~0.12, absmax 1.16e-10).
// Single new variable vs R10: L3-warm state prefetch — per kt, 4 coalesced
// kept-alive float4 loads/thread walk the block's Im/Ia/Is/rf footprint
// (arr = kt>>2, wave-uniform), issued AFTER the barrier so they drain at the
// NEXT kt's vmcnt(0) (~full tile of latency slack). Uses the GEMM phase's
// idle HBM (27% busy) so the epilogue's 134 MB read-burst hits L3.
// All resident state = 134 MB < 256 MB L3.

constexpr int SRCROW = 2048;            // fp8 row stride of X / W = 2048 B

// exact-binary / trivially-representable constants
constexpr float I0f     = 5e-14f;
constexpr float c_Itau  = 1e-12f;
constexpr float c_Igain = 1e-12f;
constexpr float c_Idc   = 1e-12f;
constexpr float c_Ith   = 1e-12f;
constexpr float c_dt    = 1e-3f;
constexpr float c_beta  = 0.05f;                                  // I0/Itau
constexpr float c_rItau = 1e12f;                                  // 1/Itau
const float c_ndt_tsyn  = (float)(-1e-3 / (0.025 / 0.705 * 2.0)); // -dt/tau_syn
const float c_dt_tmem   = (float)( 1e-3 / (0.025 / 0.705 * 3.0)); //  dt/tau_mem
const float c_p2        = (float)(0.705 / 1.705);                 // kappa/(kappa+1)

__device__ __forceinline__ void neuron_step(
    float nA, float nS, float Im, float Ia, float Is, float rf,
    float IwA, float IwS, float c0h,
    float& o0, float& o1, float& o2, float& o3, float& o4)
{
    float Ia1 = fmaf(IwA, nA, Ia);
    float Is1 = fmaf(IwS, nS, Is);

    float Iin = c_Idc + Ia1 + I0f - Is1;
    Iin = (rf <= 0.0f) ? Iin : 0.0f;
    Iin = fmaxf(Iin, I0f);

    float fim = c0h * __powf(Im, c_p2) * c_rItau * (Im + c_Igain);

    float num = (Iin - c_Itau - I0f) - Im - c_beta * Im + fim;
    float r   = __builtin_amdgcn_rcpf(Im + c_Igain);
    float Im1 = fmaxf(fmaf(num * Im * r, c_dt_tmem, Im), I0f);

    float IaO = fmaxf(fmaf(Ia, c_ndt_tsyn, Ia1), I0f);
    float IsO = fmaxf(fmaf(Is, c_ndt_tsyn, Is1), I0f);

    float spk = (Im1 - c_Ith > 0.0f) ? 1.0f : 0.0f;
    float ImO = (spk > 0.0f) ? I0f : Im1;
    float rf1 = fmaxf(rf - c_dt, 0.0f);
    float rfO = (spk > 0.0f) ? 0.0f : rf1;

    o0 = spk; o1 = ImO; o2 = IaO; o3 = IsO; o4 = rfO;
}

__device__ __forceinline__ i32x8 ld_frag(const char* base, int su0, int su1) {
    i32x4 lo = *(const i32x4*)(base + su0);
    i32x4 hi = *(const i32x4*)(base + su1);
    i32x8 v = { lo[0], lo[1], lo[2], lo[3], hi[0], hi[1], hi[2], hi[3] };
    return v;
}

__global__ __launch_bounds__(256, 2) void dpi_fused(
    const unsigned char* __restrict__ Xq,
    const unsigned char* __restrict__ Waq,
    const unsigned char* __restrict__ Wsq,
    const float* __restrict__ pIwA, const float* __restrict__ pIwS,
    const float* __restrict__ Imem_in, const float* __restrict__ Iampa_in,
    const float* __restrict__ Ishunt_in, const float* __restrict__ refr_in,
    float* __restrict__ out, float c0h)
{
    // union: K-loop A|Ba|Bs 3x16KB = 49152 B ; epilogue 2x[64][133] f32 = 68096 B
    __shared__ __align__(16) char lds[68096];
    char* As  = lds;            // [128 rows][128 fp8]
    char* Bas = lds + 16384;
    char* Bss = lds + 32768;

    const int tid  = threadIdx.x;
    const int lane = tid & 63;
    const int wid  = tid >> 6;
    const int wr   = wid >> 1;     // wave row (0..1) -> 64 rows
    const int wc   = wid & 1;      // wave col (0..1) -> 64 cols
    const int bn   = blockIdx.x;   // 0..15  (N tiles of 128)
    const int bm   = blockIdx.y;   // 0..31  (M tiles of 128)

    // --- staging: A, Ba, Bs each 16 KB = 16 x 1KB segs (4 per wave) ---
    int offq[4];
    const unsigned char* srcA[4];
    const unsigned char* srcBa[4];
    const unsigned char* srcBs[4];
#pragma unroll
    for (int q = 0; q < 4; ++q) {
        int off = (q * 4 + wid) * 1024 + lane * 16;   // linear LDS dest byte offset
        int row = off >> 7;                            // 0..127 (128 B per row)
        int cG  = ((off >> 4) & 7) ^ (row & 7);        // swizzled global 16B unit
        offq[q]  = off;
        srcA[q]  = Xq  + (size_t)(bm * 128 + row) * SRCROW + cG * 16;
        srcBa[q] = Waq + (size_t)(bn * 128 + row) * SRCROW + cG * 16;
        srcBs[q] = Wsq + (size_t)(bn * 128 + row) * SRCROW + cG * 16;
    }

    // --- fragment addressing: lane fr = M/N idx, g = k-32-block ---
    const int fr = lane & 15;
    const int g  = lane >> 4;
    const int su0 = (((g << 1)    ) ^ (fr & 7)) << 4;   // swizzled 16B unit, k 0..15
    const int su1 = (((g << 1) | 1) ^ (fr & 7)) << 4;   // k 16..31
    int rowA[4], rowB[4];
#pragma unroll
    for (int m = 0; m < 4; ++m)
        rowA[m] = (wr * 64 + m * 16 + fr) * 128;
#pragma unroll
    for (int n = 0; n < 4; ++n)
        rowB[n] = (wc * 64 + n * 16 + fr) * 128;

    f32x4 accA[4][4] = {};
    f32x4 accS[4][4] = {};

    constexpr int SC1 = 0x7F7F7F7F;     // E8M0 unit scale in every byte

    for (int kt = 0; kt < 16; ++kt) {
        if (kt) __syncthreads();                       // previous tile fully consumed
#pragma unroll
        for (int q = 0; q < 4; ++q) {
            __builtin_amdgcn_global_load_lds(
                (__attribute__((address_space(1))) void*)(srcA[q] + kt * 128),
                (__attribute__((address_space(3))) void*)(As + offq[q]), 16, 0, 0);
            __builtin_amdgcn_global_load_lds(
                (__attribute__((address_space(1))) void*)(srcBa[q] + kt * 128),
                (__attribute__((address_space(3))) void*)(Bas + offq[q]), 16, 0, 0);
            __builtin_amdgcn_global_load_lds(
                (__attribute__((address_space(1))) void*)(srcBs[q] + kt * 128),
                (__attribute__((address_space(3))) void*)(Bss + offq[q]), 16, 0, 0);
        }
        asm volatile("s_waitcnt vmcnt(0)" ::: "memory");
        __syncthreads();                               // tile visible to all waves

        // ---- L3-warm prefetch of epilogue state (kept alive, discarded) ----
        // Issued after the barrier -> drains at NEXT kt's vmcnt(0) (~1 tile of
        // slack >> 900cyc HBM latency). 16 KB/kt/block; 64 KB per array per
        // 4 kts; all 4 arrays over 16 kts = exactly the block's footprint.
        {
            int arr = kt >> 2;                         // wave-uniform
            const float* sb = (arr == 0) ? Imem_in : (arr == 1) ? Iampa_in
                            : (arr == 2) ? Ishunt_in : refr_in;
#pragma unroll
            for (int q = 0; q < 4; ++q) {
                int rem = ((kt & 3) << 10) + (q << 8) + tid;   // 0..4095
                int row = rem >> 5, c4 = rem & 31;             // coalesced 1KB/instr
                f32x4 pv = *(const f32x4*)(sb +
                    ((size_t)(bm * 128 + row) << 11) + (size_t)bn * 128 + (c4 << 2));
                asm volatile("" :: "v"(pv[0]), "v"(pv[1]), "v"(pv[2]), "v"(pv[3]));
            }
        }

        i32x8 bav[4], bsv[4];
#pragma unroll
        for (int n = 0; n < 4; ++n) {
            bav[n] = ld_frag(Bas + rowB[n], su0, su1);
            bsv[n] = ld_frag(Bss + rowB[n], su0, su1);
        }
#pragma unroll
        for (int m = 0; m < 4; ++m) {
            i32x8 av = ld_frag(As + rowA[m], su0, su1);
#pragma unroll
            for (int n = 0; n < 4; ++n) {
                accA[m][n] = __builtin_amdgcn_mfma_scale_f32_16x16x128_f8f6f4(
                    av, bav[n], accA[m][n], 0, 0, 0, SC1, 0, SC1);
                accS[m][n] = __builtin_amdgcn_mfma_scale_f32_16x16x128_f8f6f4(
                    av, bsv[n], accS[m][n], 0, 0, 0, SC1, 0, SC1);
            }
        }
    }

    // ---------- vectorized epilogue: LDS transpose + float4 streams ----------
    const float IwA = pIwA[0];
    const float IwS = pIwS[0];

    float* ldsA = (float*)lds;              // [64][133] f32, 34048 B
    float* ldsS = (float*)(lds + 34048);    // [64][133] f32

    const float4* Im4 = (const float4*)Imem_in;
    const float4* Ia4 = (const float4*)Iampa_in;
    const float4* Is4 = (const float4*)Ishunt_in;
    const float4* Rf4 = (const float4*)refr_in;
    float4* o_spk = (float4*)out;
    float4* o_mem = (float4*)(out + (size_t)8388608);
    float4* o_amp = (float4*)(out + (size_t)16777216);
    float4* o_shn = (float4*)(out + (size_t)25165824);
    float4* o_ref = (float4*)(out + (size_t)33554432);

#pragma unroll
    for (int h = 0; h < 2; ++h) {           // row-half pass: rows [64h, 64h+64)
        __syncthreads();                     // LDS free (K-loop done / prev pass read)
        if (wr == h) {                       // wave-uniform branch; both wc waves write
#pragma unroll
            for (int m = 0; m < 4; ++m)
#pragma unroll
                for (int n = 0; n < 4; ++n)
#pragma unroll
                    for (int r = 0; r < 4; ++r) {
                        int R = m * 16 + (lane >> 4) * 4 + r;     // 0..63 local row
                        int C = wc * 64 + n * 16 + (lane & 15);   // 0..127 local col
                        ldsA[R * 133 + C] = accA[m][n][r];
                        ldsS[R * 133 + C] = accS[m][n][r];
                    }
        }
        __syncthreads();
#pragma unroll
        for (int k = 0; k < 8; ++k) {
            int f4  = tid + 256 * k;         // 0..2047 float4-id in 64x128 half
            int r2  = f4 >> 5;               // 0..63 local row
            int c4  = f4 & 31;               // 0..31 float4 col
            float4 nA4 = *(const float4*)&ldsA[r2 * 133 + c4 * 4];
            float4 nS4 = *(const float4*)&ldsS[r2 * 133 + c4 * 4];
            int    B   = bm * 128 + h * 64 + r2;
            size_t g4  = (size_t)B * 512 + (size_t)bn * 32 + c4;

            float4 im = Im4[g4], ia = Ia4[g4], is = Is4[g4], rf = Rf4[g4];
            float4 spk, mem, amp, shn, ref;
            neuron_step(nA4.x, nS4.x, im.x, ia.x, is.x, rf.x, IwA, IwS, c0h,
                        spk.x, mem.x, amp.x, shn.x, ref.x);
            neuron_step(nA4.y, nS4.y, im.y, ia.y, is.y, rf.y, IwA, IwS, c0h,
                        spk.y, mem.y, amp.y, shn.y, ref.y);
            neuron_step(nA4.z, nS4.z, im.z, ia.z, is.z, rf.z, IwA, IwS, c0h,
                        spk.z, mem.z, amp.z, shn.z, ref.z);
            neuron_step(nA4.w, nS4.w, im.w, ia.w, is.w, rf.w, IwA, IwS, c0h,
                        spk.w, mem.w, amp.w, shn.w, ref.w);
            o_spk[g4] = spk;
            o_mem[g4] = mem;
            o_amp[g4] = amp;
            o_shn[g4] = shn;
            o_ref[g4] = ref;
        }
    }
}

extern "C" void kernel_launch(void* const* d_in, const int* in_sizes, int n_in,
                              void* d_out, int out_size, void* d_ws, size_t ws_size,
                              hipStream_t stream) {
    const float* X    = (const float*)d_in[0];
    const float* Wa   = (const float*)d_in[1];
    const float* Ws   = (const float*)d_in[2];
    const float* IwA  = (const float*)d_in[3];
    const float* IwS  = (const float*)d_in[4];
    const float* Imem = (const float*)d_in[5];
    const float* Iamp = (const float*)d_in[6];
    const float* Ishn = (const float*)d_in[7];
    const float* refr = (const float*)d_in[8];

    unsigned char* Xq  = (unsigned char*)d_ws;              // 8.39 MB fp8
    unsigned char* Waq = Xq + (size_t)4096 * 2048;          // 4.19 MB fp8
    unsigned char* Wsq = Waq + (size_t)2048 * 2048;         // 4.19 MB fp8

    float c0h = (float)(0.5 * pow(5e-14, 1.0 / 1.705));

    convert_all<<<8192, 256, 0, stream>>>((const float4*)X, (const float4*)Wa,
                                          (const float4*)Ws,
                                          (unsigned long long*)Xq,
                                          (unsigned long long*)Waq,
                                          (unsigned long long*)Wsq);

    dim3 grid(16, 32);   // (N/128, M/128)
    dpi_fused<<<grid, 256, 0, stream>>>(Xq, Waq, Wsq, IwA, IwS,
                                        Imem, Iamp, Ishn, refr, (float*)d_out, c0h);
}

// Round 14
// 126.475 us; speedup vs baseline: 1.3245x; 1.3245x over previous
//
#include <hip/hip_runtime.h>
#include <cstdint>
#include <cstddef>
#include <cmath>

// ---------- types ----------
typedef float f32x4 __attribute__((ext_vector_type(4)));
typedef int   i32x4 __attribute__((ext_vector_type(4)));
typedef int   i32x8 __attribute__((ext_vector_type(8)));

// ---------- pass 1: f32 -> fp8 e4m3 (X), rint+fp8 (W_ampa, W_shunt) ----------
__global__ void convert_all(const float4* __restrict__ X,
                            const float4* __restrict__ Wa,
                            const float4* __restrict__ Ws,
                            unsigned long long* __restrict__ Xq,
                            unsigned long long* __restrict__ Waq,
                            unsigned long long* __restrict__ Wsq) {
    int i = blockIdx.x * 256 + threadIdx.x;
    const float4* s; unsigned long long* d; int t; bool rnd;
    if (i < 1048576)      { s = X;  d = Xq;  t = i;           rnd = false; }
    else if (i < 1572864) { s = Wa; d = Waq; t = i - 1048576; rnd = true;  }
    else                  { s = Ws; d = Wsq; t = i - 1572864; rnd = true;  }
    float4 a = s[2 * t], b = s[2 * t + 1];
    if (rnd) {
        a.x = rintf(a.x); a.y = rintf(a.y); a.z = rintf(a.z); a.w = rintf(a.w);
        b.x = rintf(b.x); b.y = rintf(b.y); b.z = rintf(b.z); b.w = rintf(b.w);
    }
    int w0 = __builtin_amdgcn_cvt_pk_fp8_f32(a.x, a.y, 0, false);
    w0     = __builtin_amdgcn_cvt_pk_fp8_f32(a.z, a.w, w0, true);
    int w1 = __builtin_amdgcn_cvt_pk_fp8_f32(b.x, b.y, 0, false);
    w1     = __builtin_amdgcn_cvt_pk_fp8_f32(b.z, b.w, w1, true);
    d[t] = ((unsigned long long)(unsigned int)w1 << 32) | (unsigned int)w0;
}

// ---------- pass 2: fused dual-GEMM (MX-fp8 K=128) + DPI neuron update ----------
// R14: BM 128->256 (fp4 abandoned after 2 unresolvable k-permutation fails).
// Grid 16x16, 512 threads = 8 waves (4M x 2N), wave tile 64x64 per matrix ->
// acc still 128 regs, per-wave schedule IDENTICAL to R10. Effect: B panels
// re-staged 16x not 32x (staging bytes/output -33%), vmcnt(0) drains per
// output halved. A rows stay 128 B -> all verified swizzle math carries over.
// LDS: A 32K | Ba 16K | Bs 16K = 64 KB, union epilogue 68096 B; 2 blocks/CU.
// Epilogue: 4 h-passes of the R10 pattern.

constexpr int SRCROW = 2048;            // fp8 row stride of X / W = 2048 B

constexpr float I0f     = 5e-14f;
constexpr float c_Itau  = 1e-12f;
constexpr float c_Igain = 1e-12f;
constexpr float c_Idc   = 1e-12f;
constexpr float c_Ith   = 1e-12f;
constexpr float c_dt    = 1e-3f;
constexpr float c_beta  = 0.05f;                                  // I0/Itau
constexpr float c_rItau = 1e12f;                                  // 1/Itau
const float c_ndt_tsyn  = (float)(-1e-3 / (0.025 / 0.705 * 2.0)); // -dt/tau_syn
const float c_dt_tmem   = (float)( 1e-3 / (0.025 / 0.705 * 3.0)); //  dt/tau_mem
const float c_p2        = (float)(0.705 / 1.705);                 // kappa/(kappa+1)

__device__ __forceinline__ void neuron_step(
    float nA, float nS, float Im, float Ia, float Is, float rf,
    float IwA, float IwS, float c0h,
    float& o0, float& o1, float& o2, float& o3, float& o4)
{
    float Ia1 = fmaf(IwA, nA, Ia);
    float Is1 = fmaf(IwS, nS, Is);

    float Iin = c_Idc + Ia1 + I0f - Is1;
    Iin = (rf <= 0.0f) ? Iin : 0.0f;
    Iin = fmaxf(Iin, I0f);

    float fim = c0h * __powf(Im, c_p2) * c_rItau * (Im + c_Igain);

    float num = (Iin - c_Itau - I0f) - Im - c_beta * Im + fim;
    float r   = __builtin_amdgcn_rcpf(Im + c_Igain);
    float Im1 = fmaxf(fmaf(num * Im * r, c_dt_tmem, Im), I0f);

    float IaO = fmaxf(fmaf(Ia, c_ndt_tsyn, Ia1), I0f);
    float IsO = fmaxf(fmaf(Is, c_ndt_tsyn, Is1), I0f);

    float spk = (Im1 - c_Ith > 0.0f) ? 1.0f : 0.0f;
    float ImO = (spk > 0.0f) ? I0f : Im1;
    float rf1 = fmaxf(rf - c_dt, 0.0f);
    float rfO = (spk > 0.0f) ? 0.0f : rf1;

    o0 = spk; o1 = ImO; o2 = IaO; o3 = IsO; o4 = rfO;
}

__device__ __forceinline__ i32x8 ld_frag(const char* base, int su0, int su1) {
    i32x4 lo = *(const i32x4*)(base + su0);
    i32x4 hi = *(const i32x4*)(base + su1);
    i32x8 v = { lo[0], lo[1], lo[2], lo[3], hi[0], hi[1], hi[2], hi[3] };
    return v;
}

__global__ __launch_bounds__(512, 2) void dpi_fused(
    const unsigned char* __restrict__ Xq,
    const unsigned char* __restrict__ Waq,
    const unsigned char* __restrict__ Wsq,
    const float* __restrict__ pIwA, const float* __restrict__ pIwS,
    const float* __restrict__ Imem_in, const float* __restrict__ Iampa_in,
    const float* __restrict__ Ishunt_in, const float* __restrict__ refr_in,
    float* __restrict__ out, float c0h)
{
    // union: K-loop A 32K | Ba 16K | Bs 16K = 65536 B ; epilogue 2x34048 = 68096 B
    __shared__ __align__(16) char lds[68096];
    char* As  = lds;            // [256 rows][128 fp8]
    char* Bas = lds + 32768;    // [128 rows][128 fp8]
    char* Bss = lds + 49152;

    const int tid  = threadIdx.x;
    const int lane = tid & 63;
    const int wid  = tid >> 6;     // 0..7
    const int wr   = wid >> 1;     // 0..3 -> 64-row slice of 256
    const int wc   = wid & 1;      // 0..1 -> 64-col slice of 128
    const int bn   = blockIdx.x;   // 0..15  (N tiles of 128)
    const int bm   = blockIdx.y;   // 0..15  (M tiles of 256)

    // --- staging: A 32KB = 32 segs (4/wave); each B 16KB = 16 segs (2/wave) ---
    int offqA[4];  const unsigned char* srcA[4];
    int offqB[2];  const unsigned char* srcBa[2];  const unsigned char* srcBs[2];
#pragma unroll
    for (int q = 0; q < 4; ++q) {
        int off = (q * 8 + wid) * 1024 + lane * 16;   // linear LDS dest byte offset
        int row = off >> 7;                            // 0..255 (128 B per row)
        int cG  = ((off >> 4) & 7) ^ (row & 7);        // swizzled global 16B unit
        offqA[q] = off;
        srcA[q]  = Xq + (size_t)(bm * 256 + row) * SRCROW + cG * 16;
    }
#pragma unroll
    for (int q = 0; q < 2; ++q) {
        int off = (q * 8 + wid) * 1024 + lane * 16;
        int row = off >> 7;                            // 0..127
        int cG  = ((off >> 4) & 7) ^ (row & 7);
        offqB[q]  = off;
        srcBa[q]  = Waq + (size_t)(bn * 128 + row) * SRCROW + cG * 16;
        srcBs[q]  = Wsq + (size_t)(bn * 128 + row) * SRCROW + cG * 16;
    }

    // --- fragment addressing: lane fr = M/N idx, g = k-32-block ---
    const int fr = lane & 15;
    const int g  = lane >> 4;
    const int su0 = (((g << 1)    ) ^ (fr & 7)) << 4;   // swizzled 16B unit, k 0..15
    const int su1 = (((g << 1) | 1) ^ (fr & 7)) << 4;   // k 16..31
    int rowA[4], rowB[4];
#pragma unroll
    for (int m = 0; m < 4; ++m)
        rowA[m] = (wr * 64 + m * 16 + fr) * 128;       // row within 256-row A tile
#pragma unroll
    for (int n = 0; n < 4; ++n)
        rowB[n] = (wc * 64 + n * 16 + fr) * 128;       // row within 128-row B tile

    f32x4 accA[4][4] = {};
    f32x4 accS[4][4] = {};

    constexpr int SC1 = 0x7F7F7F7F;     // E8M0 unit scale in every byte

    for (int kt = 0; kt < 16; ++kt) {
        if (kt) __syncthreads();                       // previous tile fully consumed
#pragma unroll
        for (int q = 0; q < 4; ++q)
            __builtin_amdgcn_global_load_lds(
                (__attribute__((address_space(1))) void*)(srcA[q] + kt * 128),
                (__attribute__((address_space(3))) void*)(As + offqA[q]), 16, 0, 0);
#pragma unroll
        for (int q = 0; q < 2; ++q) {
            __builtin_amdgcn_global_load_lds(
                (__attribute__((address_space(1))) void*)(srcBa[q] + kt * 128),
                (__attribute__((address_space(3))) void*)(Bas + offqB[q]), 16, 0, 0);
            __builtin_amdgcn_global_load_lds(
                (__attribute__((address_space(1))) void*)(srcBs[q] + kt * 128),
                (__attribute__((address_space(3))) void*)(Bss + offqB[q]), 16, 0, 0);
        }
        asm volatile("s_waitcnt vmcnt(0)" ::: "memory");
        __syncthreads();                               // tile visible to all waves

        i32x8 bav[4], bsv[4];
#pragma unroll
        for (int n = 0; n < 4; ++n) {
            bav[n] = ld_frag(Bas + rowB[n], su0, su1);
            bsv[n] = ld_frag(Bss + rowB[n], su0, su1);
        }
#pragma unroll
        for (int m = 0; m < 4; ++m) {
            i32x8 av = ld_frag(As + rowA[m], su0, su1);
#pragma unroll
            for (int n = 0; n < 4; ++n) {
                accA[m][n] = __builtin_amdgcn_mfma_scale_f32_16x16x128_f8f6f4(
                    av, bav[n], accA[m][n], 0, 0, 0, SC1, 0, SC1);
                accS[m][n] = __builtin_amdgcn_mfma_scale_f32_16x16x128_f8f6f4(
                    av, bsv[n], accS[m][n], 0, 0, 0, SC1, 0, SC1);
            }
        }
    }

    // ---------- vectorized epilogue: LDS transpose + float4 streams ----------
    const float IwA = pIwA[0];
    const float IwS = pIwS[0];

    float* ldsA = (float*)lds;              // [64][133] f32, 34048 B
    float* ldsS = (float*)(lds + 34048);    // [64][133] f32

    const float4* Im4 = (const float4*)Imem_in;
    const float4* Ia4 = (const float4*)Iampa_in;
    const float4* Is4 = (const float4*)Ishunt_in;
    const float4* Rf4 = (const float4*)refr_in;
    float4* o_spk = (float4*)out;
    float4* o_mem = (float4*)(out + (size_t)8388608);
    float4* o_amp = (float4*)(out + (size_t)16777216);
    float4* o_shn = (float4*)(out + (size_t)25165824);
    float4* o_ref = (float4*)(out + (size_t)33554432);

#pragma unroll
    for (int h = 0; h < 4; ++h) {           // row-slice pass: rows [64h, 64h+64)
        __syncthreads();                     // LDS free (K-loop done / prev pass read)
        if (wr == h) {                       // wave-uniform branch; both wc waves write
#pragma unroll
            for (int m = 0; m < 4; ++m)
#pragma unroll
                for (int n = 0; n < 4; ++n)
#pragma unroll
                    for (int r = 0; r < 4; ++r) {
                        int R = m * 16 + (lane >> 4) * 4 + r;     // 0..63 local row
                        int C = wc * 64 + n * 16 + (lane & 15);   // 0..127 local col
                        ldsA[R * 133 + C] = accA[m][n][r];
                        ldsS[R * 133 + C] = accS[m][n][r];
                    }
        }
        __syncthreads();
#pragma unroll
        for (int k = 0; k < 4; ++k) {
            int f4  = tid + 512 * k;         // 0..2047 float4-id in 64x128 slice
            int r2  = f4 >> 5;               // 0..63 local row
            int c4  = f4 & 31;               // 0..31 float4 col
            float4 nA4 = *(const float4*)&ldsA[r2 * 133 + c4 * 4];
            float4 nS4 = *(const float4*)&ldsS[r2 * 133 + c4 * 4];
            int    B   = bm * 256 + h * 64 + r2;
            size_t g4  = (size_t)B * 512 + (size_t)bn * 32 + c4;

            float4 im = Im4[g4], ia = Ia4[g4], is = Is4[g4], rf = Rf4[g4];
            float4 spk, mem, amp, shn, ref;
            neuron_step(nA4.x, nS4.x, im.x, ia.x, is.x, rf.x, IwA, IwS, c0h,
                        spk.x, mem.x, amp.x, shn.x, ref.x);
            neuron_step(nA4.y, nS4.y, im.y, ia.y, is.y, rf.y, IwA, IwS, c0h,
                        spk.y, mem.y, amp.y, shn.y, ref.y);
            neuron_step(nA4.z, nS4.z, im.z, ia.z, is.z, rf.z, IwA, IwS, c0h,
                        spk.z, mem.z, amp.z, shn.z, ref.z);
            neuron_step(nA4.w, nS4.w, im.w, ia.w, is.w, rf.w, IwA, IwS, c0h,
                        spk.w, mem.w, amp.w, shn.w, ref.w);
            o_spk[g4] = spk;
            o_mem[g4] = mem;
            o_amp[g4] = amp;
            o_shn[g4] = shn;
            o_ref[g4] = ref;
        }
    }
}

extern "C" void kernel_launch(void* const* d_in, const int* in_sizes, int n_in,
                              void* d_out, int out_size, void* d_ws, size_t ws_size,
                              hipStream_t stream) {
    const float* X    = (const float*)d_in[0];
    const float* Wa   = (const float*)d_in[1];
    const float* Ws   = (const float*)d_in[2];
    const float* IwA  = (const float*)d_in[3];
    const float* IwS  = (const float*)d_in[4];
    const float* Imem = (const float*)d_in[5];
    const float* Iamp = (const float*)d_in[6];
    const float* Ishn = (const float*)d_in[7];
    const float* refr = (const float*)d_in[8];

    unsigned char* Xq  = (unsigned char*)d_ws;              // 8.39 MB fp8
    unsigned char* Waq = Xq + (size_t)4096 * 2048;          // 4.19 MB fp8
    unsigned char* Wsq = Waq + (size_t)2048 * 2048;         // 4.19 MB fp8

    float c0h = (float)(0.5 * pow(5e-14, 1.0 / 1.705));

    convert_all<<<8192, 256, 0, stream>>>((const float4*)X, (const float4*)Wa,
                                          (const float4*)Ws,
                                          (unsigned long long*)Xq,
                                          (unsigned long long*)Waq,
                                          (unsigned long long*)Wsq);

    dim3 grid(16, 16);   // (N/128, M/256)
    dpi_fused<<<grid, 512, 0, stream>>>(Xq, Waq, Wsq, IwA, IwS,
                                        Imem, Iamp, Ishn, refr, (float*)d_out, c0h);
}

// Round 15
// 117.508 us; speedup vs baseline: 1.4256x; 1.0763x over previous
//
#include <hip/hip_runtime.h>
#include <cstdint>
#include <cstddef>
#include <cmath>

// ---------- types ----------
typedef float f32x4 __attribute__((ext_vector_type(4)));
typedef int   i32x4 __attribute__((ext_vector_type(4)));
typedef int   i32x8 __attribute__((ext_vector_type(8)));

// ---------- pass 1: f32 -> fp8 e4m3 (X), rint+fp8 (W_ampa, W_shunt) ----------
__global__ void convert_all(const float4* __restrict__ X,
                            const float4* __restrict__ Wa,
                            const float4* __restrict__ Ws,
                            unsigned long long* __restrict__ Xq,
                            unsigned long long* __restrict__ Waq,
                            unsigned long long* __restrict__ Wsq) {
    int i = blockIdx.x * 256 + threadIdx.x;
    const float4* s; unsigned long long* d; int t; bool rnd;
    if (i < 1048576)      { s = X;  d = Xq;  t = i;           rnd = false; }
    else if (i < 1572864) { s = Wa; d = Waq; t = i - 1048576; rnd = true;  }
    else                  { s = Ws; d = Wsq; t = i - 1572864; rnd = true;  }
    float4 a = s[2 * t], b = s[2 * t + 1];
    if (rnd) {
        a.x = rintf(a.x); a.y = rintf(a.y); a.z = rintf(a.z); a.w = rintf(a.w);
        b.x = rintf(b.x); b.y = rintf(b.y); b.z = rintf(b.z); b.w = rintf(b.w);
    }
    int w0 = __builtin_amdgcn_cvt_pk_fp8_f32(a.x, a.y, 0, false);
    w0     = __builtin_amdgcn_cvt_pk_fp8_f32(a.z, a.w, w0, true);
    int w1 = __builtin_amdgcn_cvt_pk_fp8_f32(b.x, b.y, 0, false);
    w1     = __builtin_amdgcn_cvt_pk_fp8_f32(b.z, b.w, w1, true);
    d[t] = ((unsigned long long)(unsigned int)w1 << 32) | (unsigned int)w0;
}

// ---------- pass 2: fused dual-GEMM (MX-fp8 K=128) + DPI neuron update ----------
// R15 == R10 exactly (verified best, 118.1 us).
// History: R11/R13 fp4 B-operand failed (mixed fp8/fp4 k-permutation);
// R12 L3 prefetch -49us; R14 BM=256 -8.4us (1 blk/CU). All reverted.
// Structure: 128x128 tile, 4 waves, BK=128 fp8, serial GLL->vmcnt(0)->barrier
// K-loop (8-phase null here per R4/R5; 256^2 template geometry-blocked by
// N=2048), MX-scaled fp8 MFMA (K=128, unit scales), XOR-swizzled staging
// (0-conflict verified), division-free neuron_step, LDS-transpose float4
// epilogue at compulsory-traffic floor.

constexpr int SRCROW = 2048;            // fp8 row stride of X / W = 2048 B

constexpr float I0f     = 5e-14f;
constexpr float c_Itau  = 1e-12f;
constexpr float c_Igain = 1e-12f;
constexpr float c_Idc   = 1e-12f;
constexpr float c_Ith   = 1e-12f;
constexpr float c_dt    = 1e-3f;
constexpr float c_beta  = 0.05f;                                  // I0/Itau
constexpr float c_rItau = 1e12f;                                  // 1/Itau
const float c_ndt_tsyn  = (float)(-1e-3 / (0.025 / 0.705 * 2.0)); // -dt/tau_syn
const float c_dt_tmem   = (float)( 1e-3 / (0.025 / 0.705 * 3.0)); //  dt/tau_mem
const float c_p2        = (float)(0.705 / 1.705);                 // kappa/(kappa+1)

__device__ __forceinline__ void neuron_step(
    float nA, float nS, float Im, float Ia, float Is, float rf,
    float IwA, float IwS, float c0h,
    float& o0, float& o1, float& o2, float& o3, float& o4)
{
    float Ia1 = fmaf(IwA, nA, Ia);
    float Is1 = fmaf(IwS, nS, Is);

    float Iin = c_Idc + Ia1 + I0f - Is1;
    Iin = (rf <= 0.0f) ? Iin : 0.0f;
    Iin = fmaxf(Iin, I0f);

    float fim = c0h * __powf(Im, c_p2) * c_rItau * (Im + c_Igain);

    float num = (Iin - c_Itau - I0f) - Im - c_beta * Im + fim;
    float r   = __builtin_amdgcn_rcpf(Im + c_Igain);
    float Im1 = fmaxf(fmaf(num * Im * r, c_dt_tmem, Im), I0f);

    float IaO = fmaxf(fmaf(Ia, c_ndt_tsyn, Ia1), I0f);
    float IsO = fmaxf(fmaf(Is, c_ndt_tsyn, Is1), I0f);

    float spk = (Im1 - c_Ith > 0.0f) ? 1.0f : 0.0f;
    float ImO = (spk > 0.0f) ? I0f : Im1;
    float rf1 = fmaxf(rf - c_dt, 0.0f);
    float rfO = (spk > 0.0f) ? 0.0f : rf1;

    o0 = spk; o1 = ImO; o2 = IaO; o3 = IsO; o4 = rfO;
}

__device__ __forceinline__ i32x8 ld_frag(const char* base, int su0, int su1) {
    i32x4 lo = *(const i32x4*)(base + su0);
    i32x4 hi = *(const i32x4*)(base + su1);
    i32x8 v = { lo[0], lo[1], lo[2], lo[3], hi[0], hi[1], hi[2], hi[3] };
    return v;
}

__global__ __launch_bounds__(256, 2) void dpi_fused(
    const unsigned char* __restrict__ Xq,
    const unsigned char* __restrict__ Waq,
    const unsigned char* __restrict__ Wsq,
    const float* __restrict__ pIwA, const float* __restrict__ pIwS,
    const float* __restrict__ Imem_in, const float* __restrict__ Iampa_in,
    const float* __restrict__ Ishunt_in, const float* __restrict__ refr_in,
    float* __restrict__ out, float c0h)
{
    // union: K-loop A|Ba|Bs 3x16KB = 49152 B ; epilogue 2x[64][133] f32 = 68096 B
    __shared__ __align__(16) char lds[68096];
    char* As  = lds;            // [128 rows][128 fp8]
    char* Bas = lds + 16384;
    char* Bss = lds + 32768;

    const int tid  = threadIdx.x;
    const int lane = tid & 63;
    const int wid  = tid >> 6;
    const int wr   = wid >> 1;     // wave row (0..1) -> 64 rows
    const int wc   = wid & 1;      // wave col (0..1) -> 64 cols
    const int bn   = blockIdx.x;   // 0..15  (N tiles of 128)
    const int bm   = blockIdx.y;   // 0..31  (M tiles of 128)

    // --- staging: A, Ba, Bs each 16 KB = 16 x 1KB segs (4 per wave) ---
    int offq[4];
    const unsigned char* srcA[4];
    const unsigned char* srcBa[4];
    const unsigned char* srcBs[4];
#pragma unroll
    for (int q = 0; q < 4; ++q) {
        int off = (q * 4 + wid) * 1024 + lane * 16;   // linear LDS dest byte offset
        int row = off >> 7;                            // 0..127 (128 B per row)
        int cG  = ((off >> 4) & 7) ^ (row & 7);        // swizzled global 16B unit
        offq[q]  = off;
        srcA[q]  = Xq  + (size_t)(bm * 128 + row) * SRCROW + cG * 16;
        srcBa[q] = Waq + (size_t)(bn * 128 + row) * SRCROW + cG * 16;
        srcBs[q] = Wsq + (size_t)(bn * 128 + row) * SRCROW + cG * 16;
    }

    // --- fragment addressing: lane fr = M/N idx, g = k-32-block ---
    const int fr = lane & 15;
    const int g  = lane >> 4;
    const int su0 = (((g << 1)    ) ^ (fr & 7)) << 4;   // swizzled 16B unit, k 0..15
    const int su1 = (((g << 1) | 1) ^ (fr & 7)) << 4;   // k 16..31
    int rowA[4], rowB[4];
#pragma unroll
    for (int m = 0; m < 4; ++m)
        rowA[m] = (wr * 64 + m * 16 + fr) * 128;
#pragma unroll
    for (int n = 0; n < 4; ++n)
        rowB[n] = (wc * 64 + n * 16 + fr) * 128;

    f32x4 accA[4][4] = {};
    f32x4 accS[4][4] = {};

    constexpr int SC1 = 0x7F7F7F7F;     // E8M0 unit scale in every byte

    for (int kt = 0; kt < 16; ++kt) {
        if (kt) __syncthreads();                       // previous tile fully consumed
#pragma unroll
        for (int q = 0; q < 4; ++q) {
            __builtin_amdgcn_global_load_lds(
                (__attribute__((address_space(1))) void*)(srcA[q] + kt * 128),
                (__attribute__((address_space(3))) void*)(As + offq[q]), 16, 0, 0);
            __builtin_amdgcn_global_load_lds(
                (__attribute__((address_space(1))) void*)(srcBa[q] + kt * 128),
                (__attribute__((address_space(3))) void*)(Bas + offq[q]), 16, 0, 0);
            __builtin_amdgcn_global_load_lds(
                (__attribute__((address_space(1))) void*)(srcBs[q] + kt * 128),
                (__attribute__((address_space(3))) void*)(Bss + offq[q]), 16, 0, 0);
        }
        asm volatile("s_waitcnt vmcnt(0)" ::: "memory");
        __syncthreads();                               // tile visible to all waves

        i32x8 bav[4], bsv[4];
#pragma unroll
        for (int n = 0; n < 4; ++n) {
            bav[n] = ld_frag(Bas + rowB[n], su0, su1);
            bsv[n] = ld_frag(Bss + rowB[n], su0, su1);
        }
#pragma unroll
        for (int m = 0; m < 4; ++m) {
            i32x8 av = ld_frag(As + rowA[m], su0, su1);
#pragma unroll
            for (int n = 0; n < 4; ++n) {
                accA[m][n] = __builtin_amdgcn_mfma_scale_f32_16x16x128_f8f6f4(
                    av, bav[n], accA[m][n], 0, 0, 0, SC1, 0, SC1);
                accS[m][n] = __builtin_amdgcn_mfma_scale_f32_16x16x128_f8f6f4(
                    av, bsv[n], accS[m][n], 0, 0, 0, SC1, 0, SC1);
            }
        }
    }

    // ---------- vectorized epilogue: LDS transpose + float4 streams ----------
    const float IwA = pIwA[0];
    const float IwS = pIwS[0];

    float* ldsA = (float*)lds;              // [64][133] f32, 34048 B
    float* ldsS = (float*)(lds + 34048);    // [64][133] f32

    const float4* Im4 = (const float4*)Imem_in;
    const float4* Ia4 = (const float4*)Iampa_in;
    const float4* Is4 = (const float4*)Ishunt_in;
    const float4* Rf4 = (const float4*)refr_in;
    float4* o_spk = (float4*)out;
    float4* o_mem = (float4*)(out + (size_t)8388608);
    float4* o_amp = (float4*)(out + (size_t)16777216);
    float4* o_shn = (float4*)(out + (size_t)25165824);
    float4* o_ref = (float4*)(out + (size_t)33554432);

#pragma unroll
    for (int h = 0; h < 2; ++h) {           // row-half pass: rows [64h, 64h+64)
        __syncthreads();                     // LDS free (K-loop done / prev pass read)
        if (wr == h) {                       // wave-uniform branch; both wc waves write
#pragma unroll
            for (int m = 0; m < 4; ++m)
#pragma unroll
                for (int n = 0; n < 4; ++n)
#pragma unroll
                    for (int r = 0; r < 4; ++r) {
                        int R = m * 16 + (lane >> 4) * 4 + r;     // 0..63 local row
                        int C = wc * 64 + n * 16 + (lane & 15);   // 0..127 local col
                        ldsA[R * 133 + C] = accA[m][n][r];
                        ldsS[R * 133 + C] = accS[m][n][r];
                    }
        }
        __syncthreads();
#pragma unroll
        for (int k = 0; k < 8; ++k) {
            int f4  = tid + 256 * k;         // 0..2047 float4-id in 64x128 half
            int r2  = f4 >> 5;               // 0..63 local row
            int c4  = f4 & 31;               // 0..31 float4 col
            float4 nA4 = *(const float4*)&ldsA[r2 * 133 + c4 * 4];
            float4 nS4 = *(const float4*)&ldsS[r2 * 133 + c4 * 4];
            int    B   = bm * 128 + h * 64 + r2;
            size_t g4  = (size_t)B * 512 + (size_t)bn * 32 + c4;

            float4 im = Im4[g4], ia = Ia4[g4], is = Is4[g4], rf = Rf4[g4];
            float4 spk, mem, amp, shn, ref;
            neuron_step(nA4.x, nS4.x, im.x, ia.x, is.x, rf.x, IwA, IwS, c0h,
                        spk.x, mem.x, amp.x, shn.x, ref.x);
            neuron_step(nA4.y, nS4.y, im.y, ia.y, is.y, rf.y, IwA, IwS, c0h,
                        spk.y, mem.y, amp.y, shn.y, ref.y);
            neuron_step(nA4.z, nS4.z, im.z, ia.z, is.z, rf.z, IwA, IwS, c0h,
                        spk.z, mem.z, amp.z, shn.z, ref.z);
            neuron_step(nA4.w, nS4.w, im.w, ia.w, is.w, rf.w, IwA, IwS, c0h,
                        spk.w, mem.w, amp.w, shn.w, ref.w);
            o_spk[g4] = spk;
            o_mem[g4] = mem;
            o_amp[g4] = amp;
            o_shn[g4] = shn;
            o_ref[g4] = ref;
        }
    }
}

extern "C" void kernel_launch(void* const* d_in, const int* in_sizes, int n_in,
                              void* d_out, int out_size, void* d_ws, size_t ws_size,
                              hipStream_t stream) {
    const float* X    = (const float*)d_in[0];
    const float* Wa   = (const float*)d_in[1];
    const float* Ws   = (const float*)d_in[2];
    const float* IwA  = (const float*)d_in[3];
    const float* IwS  = (const float*)d_in[4];
    const float* Imem = (const float*)d_in[5];
    const float* Iamp = (const float*)d_in[6];
    const float* Ishn = (const float*)d_in[7];
    const float* refr = (const float*)d_in[8];

    unsigned char* Xq  = (unsigned char*)d_ws;              // 8.39 MB fp8
    unsigned char* Waq = Xq + (size_t)4096 * 2048;          // 4.19 MB fp8
    unsigned char* Wsq = Waq + (size_t)2048 * 2048;         // 4.19 MB fp8

    float c0h = (float)(0.5 * pow(5e-14, 1.0 / 1.705));

    convert_all<<<8192, 256, 0, stream>>>((const float4*)X, (const float4*)Wa,
                                          (const float4*)Ws,
                                          (unsigned long long*)Xq,
                                          (unsigned long long*)Waq,
                                          (unsigned long long*)Wsq);

    dim3 grid(16, 32);   // (N/128, M/128)
    dpi_fused<<<grid, 256, 0, stream>>>(Xq, Waq, Wsq, IwA, IwS,
                                        Imem, Iamp, Ishn, refr, (float*)d_out, c0h);
}